// Round 3
// baseline (1156.933 us; speedup 1.0000x reference)
//
#include <hip/hip_runtime.h>

// Problem constants (fixed by the reference setup_inputs()):
//   B=4, Q_LEN=8192, K_LEN=8192, N_SEG=8, WINDOW=1024, OFFSET=0
// Harness dtype mapping (measured R2): bool output -> int32 (absmax was
// exactly float(1.0).view(int32)-1). bool input assumed int32 likewise.
#define QL 8192
#define KL 8192
#define BB 4
#define K4 (KL / 4)

// One thread per int4 of output. Layout [B, Q, K] row-major, so the
// flat int4 index i maps as: k4 = i & (K4-1); q = (i>>11) & (QL-1);
// b = i >> 24.  Within a wave, 64 consecutive i4s = 256 consecutive k,
// same q -> q/b are wave-uniform, band check diverges only at band edges.
__global__ __launch_bounds__(256) void mask_kernel(
    const int* __restrict__ expl,     // explicit_mask [Q,K] as int32 0/1
    const int* __restrict__ qseg,     // q_segment_ids [B,Q]
    const int* __restrict__ kseg,     // kv_segment_ids [B,K]
    const int* __restrict__ p_off,    // causal_offset scalar
    const int* __restrict__ p_win,    // window scalar
    int* __restrict__ out)            // [B,Q,K] int32 0/1
{
    const int offset = *p_off;
    const int window = *p_win;

    const long long i = (long long)blockIdx.x * 256 + threadIdx.x;  // i4 index
    const int k4 = (int)(i & (K4 - 1));
    const long long qb = i >> 11;          // = b*QL + q
    const int q = (int)(qb & (QL - 1));
    const int b = (int)(qb >> 13);
    const int k0 = k4 << 2;

    // Nonzero region: diff = q-k must satisfy diff >= max(0,-offset) (causal
    // AND sw lower bound) and diff <= window-1  ->  k in [lo, hi].
    const int dmin = (-offset > 0) ? -offset : 0;
    const int lo = q - (window - 1);
    const int hi = q - dmin;

    int4 v = make_int4(0, 0, 0, 0);

    if (k0 <= hi && (k0 + 3) >= lo) {
        const int qs = qseg[b * QL + q];
        const int4 e = *reinterpret_cast<const int4*>(expl + (long long)q * KL + k0);
        const int4 s = *reinterpret_cast<const int4*>(kseg + b * KL + k0);
        int k = k0;
        v.x = (k >= lo && k <= hi && e.x != 0 && s.x == qs) ? 1 : 0; ++k;
        v.y = (k >= lo && k <= hi && e.y != 0 && s.y == qs) ? 1 : 0; ++k;
        v.z = (k >= lo && k <= hi && e.z != 0 && s.z == qs) ? 1 : 0; ++k;
        v.w = (k >= lo && k <= hi && e.w != 0 && s.w == qs) ? 1 : 0;
    }

    reinterpret_cast<int4*>(out)[i] = v;   // out i4 index == i (same layout)
}

extern "C" void kernel_launch(void* const* d_in, const int* in_sizes, int n_in,
                              void* d_out, int out_size, void* d_ws, size_t ws_size,
                              hipStream_t stream) {
    // setup_inputs() dict order:
    //   0: explicit_mask [Q,K] (bool -> int32)
    //   1: q_segment_ids [B,Q] int32
    //   2: kv_segment_ids [B,K] int32
    //   3: q_len (scalar)  4: k_len (scalar)  5: causal_offset  6: window
    const int* expl  = (const int*)d_in[0];
    const int* qseg  = (const int*)d_in[1];
    const int* kseg  = (const int*)d_in[2];
    const int* p_off = (const int*)d_in[5];
    const int* p_win = (const int*)d_in[6];
    int* out = (int*)d_out;

    const long long total_i4 = (long long)BB * QL * K4;   // 67,108,864
    const int block = 256;
    const long long grid = total_i4 / block;              // 262,144 (exact)

    mask_kernel<<<dim3((unsigned)grid), dim3(block), 0, stream>>>(
        expl, qseg, kseg, p_off, p_win, out);
}